// Round 4
// baseline (295.867 us; speedup 1.0000x reference)
//
#include <hip/hip_runtime.h>
#include <math.h>

// BalancedLoss: B=65536 rows, C=512 classes, pos_prop per class.
// loss = mean(bce(pred,target) * w), w depends only on (column, target value).
//
// R2: fast softplus (v_exp/v_log). R3: striped atomics -> 107us, but WRITE_SIZE
//     showed 3.1M atomics x 16B = 50MB of coherent-fabric RMW = the whole 107us.
// R4: kill the atomics. Partial kernel writes per-block partials with plain
//     coalesced stores (P[blk][1536], 6.3MB); a second kernel (8 blocks x 64
//     cols) sums partials, computes weights + final term, 1 atomic per block.

constexpr int C = 512;
constexpr int C4 = 128;      // float4s per row
constexpr int PSTRIDE = 3 * C;   // 1536 floats per partial slot

__device__ __forceinline__ float softplus_neg_abs(float p) {
    // log(1 + exp(-|p|)) via HW exp/log; arg in (1,2], abs err ~1e-7.
    return __logf(1.0f + __expf(-fabsf(p)));
}

__global__ __launch_bounds__(512, 4) void bl_partial(
    const float4* __restrict__ pred4, const float4* __restrict__ targ4,
    float* __restrict__ P, int rows_per_block)
{
    const int tid = threadIdx.x;
    const int col4 = tid & (C4 - 1);   // which float4 within the row
    const int rowlane = tid >> 7;      // 0..3 (4 rows in flight per block)
    const long long row0 = (long long)blockIdx.x * rows_per_block;

    float4 a_s1 = {0.f, 0.f, 0.f, 0.f};
    float4 a_st = {0.f, 0.f, 0.f, 0.f};
    float4 a_c1 = {0.f, 0.f, 0.f, 0.f};

    #pragma unroll 8
    for (int r = rowlane; r < rows_per_block; r += 4) {
        size_t idx = (size_t)(row0 + r) * C4 + col4;
        float4 p = pred4[idx];
        float4 t = targ4[idx];
        float b;
        b = fmaxf(p.x, 0.f) + softplus_neg_abs(p.x) - p.x * t.x;
        a_st.x += b; a_s1.x += b * t.x; a_c1.x += t.x;
        b = fmaxf(p.y, 0.f) + softplus_neg_abs(p.y) - p.y * t.y;
        a_st.y += b; a_s1.y += b * t.y; a_c1.y += t.y;
        b = fmaxf(p.z, 0.f) + softplus_neg_abs(p.z) - p.z * t.z;
        a_st.z += b; a_s1.z += b * t.z; a_c1.z += t.z;
        b = fmaxf(p.w, 0.f) + softplus_neg_abs(p.w) - p.w * t.w;
        a_st.w += b; a_s1.w += b * t.w; a_c1.w += t.w;
    }

    // Reduce the 4 rowlanes sharing each column-quad, then PLAIN float4 stores
    // into this block's private partial slot (no atomics, no init required).
    __shared__ float4 red[3][512];   // 24 KiB
    red[0][tid] = a_s1;
    red[1][tid] = a_st;
    red[2][tid] = a_c1;
    __syncthreads();
    if (tid < C4) {
        float* slot = P + (size_t)blockIdx.x * PSTRIDE;
        #pragma unroll
        for (int a = 0; a < 3; ++a) {
            float4 v0 = red[a][tid];
            float4 v1 = red[a][tid + 128];
            float4 v2 = red[a][tid + 256];
            float4 v3 = red[a][tid + 384];
            float4 v;
            v.x = v0.x + v1.x + v2.x + v3.x;
            v.y = v0.y + v1.y + v2.y + v3.y;
            v.z = v0.z + v1.z + v2.z + v3.z;
            v.w = v0.w + v1.w + v2.w + v3.w;
            ((float4*)(slot + a * C))[tid] = v;   // coalesced 2KB per array
        }
    }
}

// 8 blocks x 512 threads; block owns 64 columns. Sums P over G rows,
// computes per-column weights + term, one atomicAdd(out) per block.
__global__ __launch_bounds__(512) void bl_reduce(
    const float* __restrict__ P, const float* __restrict__ pos_prop,
    float* __restrict__ out, int G, float Bf)
{
    const int tid = threadIdx.x;
    const int k = tid >> 4;          // 0..31: row-strided lane
    const int g = tid & 15;          // 0..15: float4 within the 64 columns
    const int colbase = blockIdx.x * 64;

    float4 s1 = {0,0,0,0}, st = {0,0,0,0}, n1 = {0,0,0,0};
    for (int r = k; r < G; r += 32) {
        const float* row = P + (size_t)r * PSTRIDE + colbase;
        float4 a = ((const float4*)(row))[g];
        float4 b = ((const float4*)(row + C))[g];
        float4 c = ((const float4*)(row + 2 * C))[g];
        s1.x += a.x; s1.y += a.y; s1.z += a.z; s1.w += a.w;
        st.x += b.x; st.y += b.y; st.z += b.z; st.w += b.w;
        n1.x += c.x; n1.y += c.y; n1.z += c.z; n1.w += c.w;
    }

    __shared__ float4 red[3][512];   // 24 KiB
    red[0][tid] = s1; red[1][tid] = st; red[2][tid] = n1;
    __syncthreads();

    __shared__ float cs1[64], cst[64], cn1[64];
    if (tid < 16) {
        float4 rs = {0,0,0,0}, rt = {0,0,0,0}, rn = {0,0,0,0};
        for (int kk = 0; kk < 32; ++kk) {
            float4 a = red[0][kk * 16 + tid];
            float4 b = red[1][kk * 16 + tid];
            float4 c = red[2][kk * 16 + tid];
            rs.x += a.x; rs.y += a.y; rs.z += a.z; rs.w += a.w;
            rt.x += b.x; rt.y += b.y; rt.z += b.z; rt.w += b.w;
            rn.x += c.x; rn.y += c.y; rn.z += c.z; rn.w += c.w;
        }
        ((float4*)cs1)[tid] = rs;
        ((float4*)cst)[tid] = rt;
        ((float4*)cn1)[tid] = rn;
    }
    __syncthreads();

    if (tid < 64) {
        float s1c = cs1[tid], stc = cst[tid], n1c = cn1[tid];
        float bal = pos_prop[colbase + tid] * Bf;
        float n0 = Bf - n1c;
        float S0 = stc - s1c;
        float w1, w0;
        if (n1c >= bal) {              // positives are majority
            w1 = bal / n1c;
            w0 = (n0 > 0.f) ? (Bf - bal) / fmaxf(n0, 1.f) : 1.f;
        } else {                       // negatives are majority (n0 > B-bal >= 0)
            w0 = bal / n0;
            w1 = (n1c > 0.f) ? (Bf - bal) / fmaxf(n1c, 1.f) : 1.f;
        }
        float term = w1 * s1c + w0 * S0;
        #pragma unroll
        for (int off = 32; off > 0; off >>= 1)
            term += __shfl_down(term, off, 64);
        if (tid == 0)
            atomicAdd(out, term / (Bf * (float)C));   // 8 atomics total
    }
}

extern "C" void kernel_launch(void* const* d_in, const int* in_sizes, int n_in,
                              void* d_out, int out_size, void* d_ws, size_t ws_size,
                              hipStream_t stream) {
    const float* pred     = (const float*)d_in[0];
    const float* target   = (const float*)d_in[1];
    const float* pos_prop = (const float*)d_in[2];
    float* out = (float*)d_out;
    float* P = (float*)d_ws;

    const int Brows = in_sizes[0] / C;     // 65536
    int grid = 1024;                       // P = 1024*6KB = 6.3 MB
    while ((size_t)grid * PSTRIDE * sizeof(float) > ws_size && grid > 8)
        grid >>= 1;                        // deterministic in ws_size
    const int rpb = Brows / grid;          // 64 rows per block at grid=1024

    hipMemsetAsync(d_out, 0, sizeof(float), stream);
    bl_partial<<<grid, 512, 0, stream>>>((const float4*)pred, (const float4*)target, P, rpb);
    bl_reduce<<<C / 64, 512, 0, stream>>>(P, pos_prop, out, grid, (float)Brows);
}

// Round 5
// 293.894 us; speedup vs baseline: 1.0067x; 1.0067x over previous
//
#include <hip/hip_runtime.h>
#include <math.h>

// BalancedLoss: B=65536 rows, C=512 classes, pos_prop per class.
// loss = mean(bce(pred,target) * w), w depends only on (column, target value).
//
// R2: fast softplus (v_exp/v_log). R3: striped atomics. R4: plain-store partials
//     (WRITE_SIZE 49->6 MB) -- time unchanged at 107us: kernel is LATENCY-bound
//     (VGPR=36, loads issued in pairs with waitcnt between; VALU 18%, HBM 16%).
// R5: explicit 8-load batches (4 rows x pred+targ) issued before any use ->
//     8KB outstanding per wave; launch_bounds(512,4) so the batch gets VGPRs.
//     bl_reduce: 16 blocks + 12-load batches for the same reason.

constexpr int C = 512;
constexpr int C4 = 128;          // float4s per row
constexpr int PSTRIDE = 3 * C;   // 1536 floats per partial slot

__device__ __forceinline__ float softplus_neg_abs(float p) {
    // log(1 + exp(-|p|)) via v_exp/v_log; arg in (1,2], abs err ~1e-7.
    return __logf(1.0f + __expf(-fabsf(p)));
}

__device__ __forceinline__ void acc4(const float4& p, const float4& t,
                                     float4& a_s1, float4& a_st, float4& a_c1) {
    float b;
    b = fmaxf(p.x, 0.f) + softplus_neg_abs(p.x) - p.x * t.x;
    a_st.x += b; a_s1.x += b * t.x; a_c1.x += t.x;
    b = fmaxf(p.y, 0.f) + softplus_neg_abs(p.y) - p.y * t.y;
    a_st.y += b; a_s1.y += b * t.y; a_c1.y += t.y;
    b = fmaxf(p.z, 0.f) + softplus_neg_abs(p.z) - p.z * t.z;
    a_st.z += b; a_s1.z += b * t.z; a_c1.z += t.z;
    b = fmaxf(p.w, 0.f) + softplus_neg_abs(p.w) - p.w * t.w;
    a_st.w += b; a_s1.w += b * t.w; a_c1.w += t.w;
}

__global__ __launch_bounds__(512, 4) void bl_partial(
    const float4* __restrict__ pred4, const float4* __restrict__ targ4,
    float* __restrict__ P, int rows_per_block)   // rows_per_block % 16 == 0
{
    const int tid = threadIdx.x;
    const int col4 = tid & (C4 - 1);   // which float4 within the row
    const int rowlane = tid >> 7;      // 0..3
    const long long row0 = (long long)blockIdx.x * rows_per_block;

    float4 a_s1 = {0.f, 0.f, 0.f, 0.f};
    float4 a_st = {0.f, 0.f, 0.f, 0.f};
    float4 a_c1 = {0.f, 0.f, 0.f, 0.f};

    for (int rb = 0; rb < rows_per_block; rb += 16) {
        size_t base = (size_t)(row0 + rb + rowlane) * C4 + col4;
        // 8 independent loads, no consumer between them -> 8 KB in flight.
        float4 p0 = pred4[base];
        float4 p1 = pred4[base + 4 * C4];
        float4 p2 = pred4[base + 8 * C4];
        float4 p3 = pred4[base + 12 * C4];
        float4 t0 = targ4[base];
        float4 t1 = targ4[base + 4 * C4];
        float4 t2 = targ4[base + 8 * C4];
        float4 t3 = targ4[base + 12 * C4];
        acc4(p0, t0, a_s1, a_st, a_c1);
        acc4(p1, t1, a_s1, a_st, a_c1);
        acc4(p2, t2, a_s1, a_st, a_c1);
        acc4(p3, t3, a_s1, a_st, a_c1);
    }

    // Reduce the 4 rowlanes sharing each column-quad, then plain float4 stores
    // into this block's private partial slot.
    __shared__ float4 red[3][512];   // 24 KiB
    red[0][tid] = a_s1;
    red[1][tid] = a_st;
    red[2][tid] = a_c1;
    __syncthreads();
    if (tid < C4) {
        float* slot = P + (size_t)blockIdx.x * PSTRIDE;
        #pragma unroll
        for (int a = 0; a < 3; ++a) {
            float4 v0 = red[a][tid];
            float4 v1 = red[a][tid + 128];
            float4 v2 = red[a][tid + 256];
            float4 v3 = red[a][tid + 384];
            float4 v;
            v.x = v0.x + v1.x + v2.x + v3.x;
            v.y = v0.y + v1.y + v2.y + v3.y;
            v.z = v0.z + v1.z + v2.z + v3.z;
            v.w = v0.w + v1.w + v2.w + v3.w;
            ((float4*)(slot + a * C))[tid] = v;   // coalesced
        }
    }
}

// 16 blocks x 512 threads; block owns 32 columns (8 float4). Sums P over G
// rows (G % 256 == 0) with 12-load batches, computes weights + term,
// one atomicAdd(out) per block.
__global__ __launch_bounds__(512) void bl_reduce(
    const float* __restrict__ P, const float* __restrict__ pos_prop,
    float* __restrict__ out, int G, float Bf)
{
    const int tid = threadIdx.x;
    const int k = tid >> 3;          // 0..63: row-lane
    const int g = tid & 7;           // 0..7: float4 within the 32 columns
    const int colbase = blockIdx.x * 32;

    float4 s1 = {0,0,0,0}, st = {0,0,0,0}, n1 = {0,0,0,0};
    for (int rb = k; rb < G; rb += 256) {
        const float* r0 = P + (size_t)(rb)       * PSTRIDE + colbase;
        const float* r1 = P + (size_t)(rb + 64)  * PSTRIDE + colbase;
        const float* r2 = P + (size_t)(rb + 128) * PSTRIDE + colbase;
        const float* r3 = P + (size_t)(rb + 192) * PSTRIDE + colbase;
        float4 a0 = ((const float4*)(r0))[g], b0 = ((const float4*)(r0 + C))[g], c0 = ((const float4*)(r0 + 2*C))[g];
        float4 a1 = ((const float4*)(r1))[g], b1 = ((const float4*)(r1 + C))[g], c1 = ((const float4*)(r1 + 2*C))[g];
        float4 a2 = ((const float4*)(r2))[g], b2 = ((const float4*)(r2 + C))[g], c2 = ((const float4*)(r2 + 2*C))[g];
        float4 a3 = ((const float4*)(r3))[g], b3 = ((const float4*)(r3 + C))[g], c3 = ((const float4*)(r3 + 2*C))[g];
        s1.x += a0.x + a1.x + a2.x + a3.x; s1.y += a0.y + a1.y + a2.y + a3.y;
        s1.z += a0.z + a1.z + a2.z + a3.z; s1.w += a0.w + a1.w + a2.w + a3.w;
        st.x += b0.x + b1.x + b2.x + b3.x; st.y += b0.y + b1.y + b2.y + b3.y;
        st.z += b0.z + b1.z + b2.z + b3.z; st.w += b0.w + b1.w + b2.w + b3.w;
        n1.x += c0.x + c1.x + c2.x + c3.x; n1.y += c0.y + c1.y + c2.y + c3.y;
        n1.z += c0.z + c1.z + c2.z + c3.z; n1.w += c0.w + c1.w + c2.w + c3.w;
    }

    __shared__ float4 red[3][512];   // 24 KiB
    red[0][tid] = s1; red[1][tid] = st; red[2][tid] = n1;
    __syncthreads();

    // Halving reduction over the 64 row-lanes (k dimension).
    for (int stride = 256; stride >= 8; stride >>= 1) {
        if (tid < stride) {
            #pragma unroll
            for (int a = 0; a < 3; ++a) {
                float4 u = red[a][tid], v = red[a][tid + stride];
                u.x += v.x; u.y += v.y; u.z += v.z; u.w += v.w;
                red[a][tid] = u;
            }
        }
        __syncthreads();
    }

    if (tid < 64) {
        float term = 0.f;
        if (tid < 32) {   // totals are floats [0..31] of red[a]
            float s1c = ((const float*)red[0])[tid];
            float stc = ((const float*)red[1])[tid];
            float n1c = ((const float*)red[2])[tid];
            float bal = pos_prop[colbase + tid] * Bf;
            float n0 = Bf - n1c;
            float S0 = stc - s1c;
            float w1, w0;
            if (n1c >= bal) {              // positives are majority
                w1 = bal / n1c;
                w0 = (n0 > 0.f) ? (Bf - bal) / fmaxf(n0, 1.f) : 1.f;
            } else {                       // negatives are majority (n0 > B-bal >= 0)
                w0 = bal / n0;
                w1 = (n1c > 0.f) ? (Bf - bal) / fmaxf(n1c, 1.f) : 1.f;
            }
            term = w1 * s1c + w0 * S0;
        }
        #pragma unroll
        for (int off = 32; off > 0; off >>= 1)
            term += __shfl_down(term, off, 64);
        if (tid == 0)
            atomicAdd(out, term / (Bf * (float)C));   // 16 atomics total
    }
}

extern "C" void kernel_launch(void* const* d_in, const int* in_sizes, int n_in,
                              void* d_out, int out_size, void* d_ws, size_t ws_size,
                              hipStream_t stream) {
    const float* pred     = (const float*)d_in[0];
    const float* target   = (const float*)d_in[1];
    const float* pos_prop = (const float*)d_in[2];
    float* out = (float*)d_out;
    float* P = (float*)d_ws;

    const int Brows = in_sizes[0] / C;     // 65536
    int grid = 1024;                       // P = 1024 * 6 KB = 6.3 MB
    while ((size_t)grid * PSTRIDE * sizeof(float) > ws_size && grid > 256)
        grid >>= 1;                        // deterministic in ws_size; G stays %256
    const int rpb = Brows / grid;          // 64 rows per block at grid=1024

    hipMemsetAsync(d_out, 0, sizeof(float), stream);
    bl_partial<<<grid, 512, 0, stream>>>((const float4*)pred, (const float4*)target, P, rpb);
    bl_reduce<<<C / 32, 512, 0, stream>>>(P, pos_prop, out, grid, (float)Brows);
}

// Round 6
// 292.300 us; speedup vs baseline: 1.0122x; 1.0055x over previous
//
#include <hip/hip_runtime.h>
#include <math.h>

// BalancedLoss: B=65536 rows, C=512 classes, pos_prop per class.
// loss = mean(bce(pred,target) * w), w depends only on (column, target value).
//
// R3: striped atomics 238->107us. R4: plain-store partials (WRITE 49->6MB),
//     time unchanged -> not atomic-bound. R5: explicit 8-load register batch;
//     compiler SANK it (VGPR 36->32), time unchanged 104us. L3-warm replays run
//     at the same 104us as HBM-fed passes => bound by CU-side fetch depth, not
//     memory BW. VALU 17%, HBM 17%, occupancy 64%: latency-bound at ~4 B/cy/CU.
// R6: global_load_lds staging (fire-and-forget DMA, no VGPR dest => compiler
//     cannot sink it). 32KB tile (8 rows x pred+targ), 4 blocks/CU, 2-barrier
//     loop; compute from LDS via conflict-free ds_read_b128.

constexpr int C = 512;
constexpr int C4 = 128;          // float4s per row
constexpr int PSTRIDE = 3 * C;   // 1536 floats per partial slot
constexpr int TR = 8;            // tile rows
constexpr int TILE_F4 = TR * C4;             // 1024 float4 per array per tile
constexpr int TILE_BYTES = TILE_F4 * 16;     // 16 KB per array
constexpr int CHUNKS = 2 * TILE_BYTES / 1024; // 32 x 1KB chunks per tile

typedef __attribute__((address_space(1))) const void global_cv;
typedef __attribute__((address_space(3))) void shared_v;

__device__ __forceinline__ float softplus_neg_abs(float p) {
    // log(1 + exp(-|p|)) via v_exp/v_log; arg in (1,2], abs err ~1e-7.
    return __logf(1.0f + __expf(-fabsf(p)));
}

__device__ __forceinline__ void acc4(const float4& p, const float4& t,
                                     float4& a_s1, float4& a_st, float4& a_c1) {
    float b;
    b = fmaxf(p.x, 0.f) + softplus_neg_abs(p.x) - p.x * t.x;
    a_st.x += b; a_s1.x += b * t.x; a_c1.x += t.x;
    b = fmaxf(p.y, 0.f) + softplus_neg_abs(p.y) - p.y * t.y;
    a_st.y += b; a_s1.y += b * t.y; a_c1.y += t.y;
    b = fmaxf(p.z, 0.f) + softplus_neg_abs(p.z) - p.z * t.z;
    a_st.z += b; a_s1.z += b * t.z; a_c1.z += t.z;
    b = fmaxf(p.w, 0.f) + softplus_neg_abs(p.w) - p.w * t.w;
    a_st.w += b; a_s1.w += b * t.w; a_c1.w += t.w;
}

__global__ __launch_bounds__(512, 4) void bl_partial(
    const float* __restrict__ pred, const float* __restrict__ targ,
    float* __restrict__ P, int rows_per_block)   // rows_per_block % TR == 0
{
    __shared__ __align__(16) char pool[2 * TILE_BYTES];   // 32 KiB; aliased below

    const int tid = threadIdx.x;
    const int lane = tid & 63;
    const int wave = tid >> 6;          // 0..7
    const long long row0 = (long long)blockIdx.x * rows_per_block;
    const int ntiles = rows_per_block / TR;

    float4 a_s1 = {0.f, 0.f, 0.f, 0.f};
    float4 a_st = {0.f, 0.f, 0.f, 0.f};
    float4 a_c1 = {0.f, 0.f, 0.f, 0.f};

    const float4* lp4 = (const float4*)pool;                 // pred tile
    const float4* lt4 = (const float4*)(pool + TILE_BYTES);  // targ tile

    for (int t = 0; t < ntiles; ++t) {
        size_t tileOff = (size_t)(row0 + (long long)t * TR) * C;  // float offset

        // Stage: wave w issues 4 fire-and-forget 1KB DMA chunks (q = w*4+j).
        // q<16 -> pred chunk q; q>=16 -> targ chunk q-16. LDS dest = pool+q*1KB
        // (wave-uniform base; HW adds lane*16). Global src = base + q*256 floats
        // + lane*4 floats. Contiguous both sides (no padding) as required.
        #pragma unroll
        for (int j = 0; j < 4; ++j) {
            int q = wave * 4 + j;
            const float* gsrc = (q < 16) ? pred : targ;
            int idx = q & 15;
            const float* gp = gsrc + tileOff + (size_t)idx * 256 + lane * 4;
            char* lp = pool + q * 1024;
            __builtin_amdgcn_global_load_lds((global_cv*)gp, (shared_v*)lp, 16, 0, 0);
        }
        __syncthreads();   // drains vmcnt: tile resident

        // Compute: thread handles f4 indices {tid, tid+512}; column quad is
        // tid&127 for both (512 % 128 == 0), rows = {tid>>7, 4 + tid>>7}.
        float4 p0 = lp4[tid];
        float4 p1 = lp4[tid + 512];
        float4 t0 = lt4[tid];
        float4 t1 = lt4[tid + 512];
        acc4(p0, t0, a_s1, a_st, a_c1);
        acc4(p1, t1, a_s1, a_st, a_c1);

        __syncthreads();   // protect LDS before next tile's DMA
    }

    // Epilogue: reduce 4 rowlanes per column-quad via LDS (alias the pool),
    // then plain coalesced float4 stores into this block's partial slot.
    float4* red = (float4*)pool;    // red[a*512 + i], 24 KiB of the 32 KiB pool
    red[0 * 512 + tid] = a_s1;
    red[1 * 512 + tid] = a_st;
    red[2 * 512 + tid] = a_c1;
    __syncthreads();
    if (tid < C4) {
        float* slot = P + (size_t)blockIdx.x * PSTRIDE;
        #pragma unroll
        for (int a = 0; a < 3; ++a) {
            float4 v0 = red[a * 512 + tid];
            float4 v1 = red[a * 512 + tid + 128];
            float4 v2 = red[a * 512 + tid + 256];
            float4 v3 = red[a * 512 + tid + 384];
            float4 v;
            v.x = v0.x + v1.x + v2.x + v3.x;
            v.y = v0.y + v1.y + v2.y + v3.y;
            v.z = v0.z + v1.z + v2.z + v3.z;
            v.w = v0.w + v1.w + v2.w + v3.w;
            ((float4*)(slot + a * C))[tid] = v;   // coalesced
        }
    }
}

// 16 blocks x 512 threads; block owns 32 columns (8 float4). Sums P over G
// rows (G % 256 == 0) with batched loads, computes weights + term,
// one atomicAdd(out) per block.
__global__ __launch_bounds__(512) void bl_reduce(
    const float* __restrict__ P, const float* __restrict__ pos_prop,
    float* __restrict__ out, int G, float Bf)
{
    const int tid = threadIdx.x;
    const int k = tid >> 3;          // 0..63: row-lane
    const int g = tid & 7;           // 0..7: float4 within the 32 columns
    const int colbase = blockIdx.x * 32;

    float4 s1 = {0,0,0,0}, st = {0,0,0,0}, n1 = {0,0,0,0};
    for (int rb = k; rb < G; rb += 256) {
        const float* r0 = P + (size_t)(rb)       * PSTRIDE + colbase;
        const float* r1 = P + (size_t)(rb + 64)  * PSTRIDE + colbase;
        const float* r2 = P + (size_t)(rb + 128) * PSTRIDE + colbase;
        const float* r3 = P + (size_t)(rb + 192) * PSTRIDE + colbase;
        float4 a0 = ((const float4*)(r0))[g], b0 = ((const float4*)(r0 + C))[g], c0 = ((const float4*)(r0 + 2*C))[g];
        float4 a1 = ((const float4*)(r1))[g], b1 = ((const float4*)(r1 + C))[g], c1 = ((const float4*)(r1 + 2*C))[g];
        float4 a2 = ((const float4*)(r2))[g], b2 = ((const float4*)(r2 + C))[g], c2 = ((const float4*)(r2 + 2*C))[g];
        float4 a3 = ((const float4*)(r3))[g], b3 = ((const float4*)(r3 + C))[g], c3 = ((const float4*)(r3 + 2*C))[g];
        s1.x += a0.x + a1.x + a2.x + a3.x; s1.y += a0.y + a1.y + a2.y + a3.y;
        s1.z += a0.z + a1.z + a2.z + a3.z; s1.w += a0.w + a1.w + a2.w + a3.w;
        st.x += b0.x + b1.x + b2.x + b3.x; st.y += b0.y + b1.y + b2.y + b3.y;
        st.z += b0.z + b1.z + b2.z + b3.z; st.w += b0.w + b1.w + b2.w + b3.w;
        n1.x += c0.x + c1.x + c2.x + c3.x; n1.y += c0.y + c1.y + c2.y + c3.y;
        n1.z += c0.z + c1.z + c2.z + c3.z; n1.w += c0.w + c1.w + c2.w + c3.w;
    }

    __shared__ float4 red[3][512];   // 24 KiB
    red[0][tid] = s1; red[1][tid] = st; red[2][tid] = n1;
    __syncthreads();

    // Halving reduction over the 64 row-lanes (k dimension).
    for (int stride = 256; stride >= 8; stride >>= 1) {
        if (tid < stride) {
            #pragma unroll
            for (int a = 0; a < 3; ++a) {
                float4 u = red[a][tid], v = red[a][tid + stride];
                u.x += v.x; u.y += v.y; u.z += v.z; u.w += v.w;
                red[a][tid] = u;
            }
        }
        __syncthreads();
    }

    if (tid < 64) {
        float term = 0.f;
        if (tid < 32) {   // totals are floats [0..31] of red[a]
            float s1c = ((const float*)red[0])[tid];
            float stc = ((const float*)red[1])[tid];
            float n1c = ((const float*)red[2])[tid];
            float bal = pos_prop[colbase + tid] * Bf;
            float n0 = Bf - n1c;
            float S0 = stc - s1c;
            float w1, w0;
            if (n1c >= bal) {              // positives are majority
                w1 = bal / n1c;
                w0 = (n0 > 0.f) ? (Bf - bal) / fmaxf(n0, 1.f) : 1.f;
            } else {                       // negatives are majority (n0 > B-bal >= 0)
                w0 = bal / n0;
                w1 = (n1c > 0.f) ? (Bf - bal) / fmaxf(n1c, 1.f) : 1.f;
            }
            term = w1 * s1c + w0 * S0;
        }
        #pragma unroll
        for (int off = 32; off > 0; off >>= 1)
            term += __shfl_down(term, off, 64);
        if (tid == 0)
            atomicAdd(out, term / (Bf * (float)C));   // 16 atomics total
    }
}

extern "C" void kernel_launch(void* const* d_in, const int* in_sizes, int n_in,
                              void* d_out, int out_size, void* d_ws, size_t ws_size,
                              hipStream_t stream) {
    const float* pred     = (const float*)d_in[0];
    const float* target   = (const float*)d_in[1];
    const float* pos_prop = (const float*)d_in[2];
    float* out = (float*)d_out;
    float* P = (float*)d_ws;

    const int Brows = in_sizes[0] / C;     // 65536
    int grid = 1024;                       // P = 1024 * 6 KB = 6.3 MB
    while ((size_t)grid * PSTRIDE * sizeof(float) > ws_size && grid > 256)
        grid >>= 1;                        // deterministic in ws_size; G stays %256
    const int rpb = Brows / grid;          // 64 rows per block at grid=1024

    hipMemsetAsync(d_out, 0, sizeof(float), stream);
    bl_partial<<<grid, 512, 0, stream>>>(pred, target, P, rpb);
    bl_reduce<<<C / 32, 512, 0, stream>>>(P, pos_prop, out, grid, (float)Brows);
}

// Round 8
// 270.853 us; speedup vs baseline: 1.0924x; 1.0792x over previous
//
#include <hip/hip_runtime.h>
#include <math.h>

// BalancedLoss: B=65536 rows, C=512 classes, pos_prop per class.
// loss = mean(bce(pred,target) * w), w depends only on (column, target value).
//
// History: R1 147us (libm VALU-bound) -> R3 107us (fast softplus + striped
// atomics) -> R4 plain stores (no change) -> R5 register batch (compiler sank
// it, no change) -> R6 global_load_lds DMA with >=128KB/CU in flight (no
// change). Conclusion: not latency-depth-bound; delivered read BW pinned at
// ~2.6 TB/s (134MB from HBM + 134MB from L3 per pass). VALU fully hidden.
// R7/R8: occupancy 65%->~100% (block 256, grid 2048, 12KB LDS) +
// nontemporal loads (nt flag). R7 failed to compile: builtin needs a native
// vector type, not HIP_vector_type -- use ext_vector_type(4) and convert.

constexpr int C = 512;
constexpr int C4 = 128;          // float4s per row
constexpr int PSTRIDE = 3 * C;   // 1536 floats per partial slot

typedef float floatv4 __attribute__((ext_vector_type(4)));

__device__ __forceinline__ float softplus_neg_abs(float p) {
    // log(1 + exp(-|p|)) via v_exp/v_log; arg in (1,2], abs err ~1e-7.
    return __logf(1.0f + __expf(-fabsf(p)));
}

__device__ __forceinline__ float4 ntload(const float4* p) {
    floatv4 v = __builtin_nontemporal_load((const floatv4*)p);
    return make_float4(v.x, v.y, v.z, v.w);
}

__device__ __forceinline__ void acc4(const float4& p, const float4& t,
                                     float4& a_s1, float4& a_st, float4& a_c1) {
    float b;
    b = fmaxf(p.x, 0.f) + softplus_neg_abs(p.x) - p.x * t.x;
    a_st.x += b; a_s1.x += b * t.x; a_c1.x += t.x;
    b = fmaxf(p.y, 0.f) + softplus_neg_abs(p.y) - p.y * t.y;
    a_st.y += b; a_s1.y += b * t.y; a_c1.y += t.y;
    b = fmaxf(p.z, 0.f) + softplus_neg_abs(p.z) - p.z * t.z;
    a_st.z += b; a_s1.z += b * t.z; a_c1.z += t.z;
    b = fmaxf(p.w, 0.f) + softplus_neg_abs(p.w) - p.w * t.w;
    a_st.w += b; a_s1.w += b * t.w; a_c1.w += t.w;
}

__global__ __launch_bounds__(256, 8) void bl_partial(
    const float4* __restrict__ pred4, const float4* __restrict__ targ4,
    float* __restrict__ P, int rows_per_block)   // rows_per_block % 4 == 0
{
    const int tid = threadIdx.x;
    const int col4 = tid & (C4 - 1);   // which float4 within the row
    const int rowlane = tid >> 7;      // 0..1 (2 rows in flight per block)
    const long long row0 = (long long)blockIdx.x * rows_per_block;

    float4 a_s1 = {0.f, 0.f, 0.f, 0.f};
    float4 a_st = {0.f, 0.f, 0.f, 0.f};
    float4 a_c1 = {0.f, 0.f, 0.f, 0.f};

    for (int r = rowlane; r < rows_per_block; r += 4) {
        size_t i0 = (size_t)(row0 + r) * C4 + col4;
        size_t i1 = (size_t)(row0 + r + 2) * C4 + col4;
        float4 p0 = ntload(pred4 + i0);
        float4 p1 = ntload(pred4 + i1);
        float4 t0 = ntload(targ4 + i0);
        float4 t1 = ntload(targ4 + i1);
        acc4(p0, t0, a_s1, a_st, a_c1);
        acc4(p1, t1, a_s1, a_st, a_c1);
    }

    // Reduce the 2 rowlanes sharing each column-quad, plain coalesced stores.
    __shared__ float4 red[3][256];   // 12 KiB
    red[0][tid] = a_s1;
    red[1][tid] = a_st;
    red[2][tid] = a_c1;
    __syncthreads();
    if (tid < C4) {
        float* slot = P + (size_t)blockIdx.x * PSTRIDE;
        #pragma unroll
        for (int a = 0; a < 3; ++a) {
            float4 v0 = red[a][tid];
            float4 v1 = red[a][tid + 128];
            float4 v;
            v.x = v0.x + v1.x;
            v.y = v0.y + v1.y;
            v.z = v0.z + v1.z;
            v.w = v0.w + v1.w;
            ((float4*)(slot + a * C))[tid] = v;   // coalesced
        }
    }
}

// 16 blocks x 512 threads; block owns 32 columns (8 float4). Sums P over G
// rows (G % 256 == 0) with batched loads, computes weights + term,
// one atomicAdd(out) per block.
__global__ __launch_bounds__(512) void bl_reduce(
    const float* __restrict__ P, const float* __restrict__ pos_prop,
    float* __restrict__ out, int G, float Bf)
{
    const int tid = threadIdx.x;
    const int k = tid >> 3;          // 0..63: row-lane
    const int g = tid & 7;           // 0..7: float4 within the 32 columns
    const int colbase = blockIdx.x * 32;

    float4 s1 = {0,0,0,0}, st = {0,0,0,0}, n1 = {0,0,0,0};
    for (int rb = k; rb < G; rb += 256) {
        const float* r0 = P + (size_t)(rb)       * PSTRIDE + colbase;
        const float* r1 = P + (size_t)(rb + 64)  * PSTRIDE + colbase;
        const float* r2 = P + (size_t)(rb + 128) * PSTRIDE + colbase;
        const float* r3 = P + (size_t)(rb + 192) * PSTRIDE + colbase;
        float4 a0 = ((const float4*)(r0))[g], b0 = ((const float4*)(r0 + C))[g], c0 = ((const float4*)(r0 + 2*C))[g];
        float4 a1 = ((const float4*)(r1))[g], b1 = ((const float4*)(r1 + C))[g], c1 = ((const float4*)(r1 + 2*C))[g];
        float4 a2 = ((const float4*)(r2))[g], b2 = ((const float4*)(r2 + C))[g], c2 = ((const float4*)(r2 + 2*C))[g];
        float4 a3 = ((const float4*)(r3))[g], b3 = ((const float4*)(r3 + C))[g], c3 = ((const float4*)(r3 + 2*C))[g];
        s1.x += a0.x + a1.x + a2.x + a3.x; s1.y += a0.y + a1.y + a2.y + a3.y;
        s1.z += a0.z + a1.z + a2.z + a3.z; s1.w += a0.w + a1.w + a2.w + a3.w;
        st.x += b0.x + b1.x + b2.x + b3.x; st.y += b0.y + b1.y + b2.y + b3.y;
        st.z += b0.z + b1.z + b2.z + b3.z; st.w += b0.w + b1.w + b2.w + b3.w;
        n1.x += c0.x + c1.x + c2.x + c3.x; n1.y += c0.y + c1.y + c2.y + c3.y;
        n1.z += c0.z + c1.z + c2.z + c3.z; n1.w += c0.w + c1.w + c2.w + c3.w;
    }

    __shared__ float4 red[3][512];   // 24 KiB
    red[0][tid] = s1; red[1][tid] = st; red[2][tid] = n1;
    __syncthreads();

    // Halving reduction over the 64 row-lanes (k dimension).
    for (int stride = 256; stride >= 8; stride >>= 1) {
        if (tid < stride) {
            #pragma unroll
            for (int a = 0; a < 3; ++a) {
                float4 u = red[a][tid], v = red[a][tid + stride];
                u.x += v.x; u.y += v.y; u.z += v.z; u.w += v.w;
                red[a][tid] = u;
            }
        }
        __syncthreads();
    }

    if (tid < 64) {
        float term = 0.f;
        if (tid < 32) {   // totals are floats [0..31] of red[a]
            float s1c = ((const float*)red[0])[tid];
            float stc = ((const float*)red[1])[tid];
            float n1c = ((const float*)red[2])[tid];
            float bal = pos_prop[colbase + tid] * Bf;
            float n0 = Bf - n1c;
            float S0 = stc - s1c;
            float w1, w0;
            if (n1c >= bal) {              // positives are majority
                w1 = bal / n1c;
                w0 = (n0 > 0.f) ? (Bf - bal) / fmaxf(n0, 1.f) : 1.f;
            } else {                       // negatives are majority (n0 > B-bal >= 0)
                w0 = bal / n0;
                w1 = (n1c > 0.f) ? (Bf - bal) / fmaxf(n1c, 1.f) : 1.f;
            }
            term = w1 * s1c + w0 * S0;
        }
        #pragma unroll
        for (int off = 32; off > 0; off >>= 1)
            term += __shfl_down(term, off, 64);
        if (tid == 0)
            atomicAdd(out, term / (Bf * (float)C));   // 16 atomics total
    }
}

extern "C" void kernel_launch(void* const* d_in, const int* in_sizes, int n_in,
                              void* d_out, int out_size, void* d_ws, size_t ws_size,
                              hipStream_t stream) {
    const float* pred     = (const float*)d_in[0];
    const float* target   = (const float*)d_in[1];
    const float* pos_prop = (const float*)d_in[2];
    float* out = (float*)d_out;
    float* P = (float*)d_ws;

    const int Brows = in_sizes[0] / C;     // 65536
    int grid = 2048;                       // P = 2048 * 6 KB = 12.6 MB
    while ((size_t)grid * PSTRIDE * sizeof(float) > ws_size && grid > 256)
        grid >>= 1;                        // deterministic in ws_size; G stays %256
    const int rpb = Brows / grid;          // 32 rows per block at grid=2048

    (void)hipMemsetAsync(d_out, 0, sizeof(float), stream);
    bl_partial<<<grid, 256, 0, stream>>>((const float4*)pred, (const float4*)target, P, rpb);
    bl_reduce<<<C / 32, 512, 0, stream>>>(P, pos_prop, out, grid, (float)Brows);
}